// Round 13
// baseline (80.954 us; speedup 1.0000x reference)
//
#include <hip/hip_runtime.h>
#include <hip/hip_bf16.h>

#define NNODES 4096
#define CAP 256

// R11 lesson: grid.sync() ~100+us; use dispatches. R12 lesson: D2 was
// latency-bound (ILP=1 gather chains, scalar W1 loads) -> this round adds ILP.

// ---------------------------------------------------------------------------
// Phase 1 (fused): blocks [0,4096) = edge extraction rows (HBM-bound);
// blocks [4096,5120) = layer-0 GEMM tiles + fused scores0 (VALU-bound).
// ---------------------------------------------------------------------------
__global__ __launch_bounds__(256) void phase1_kernel(
    const float* __restrict__ mask, int* __restrict__ deg, int* __restrict__ cols,
    const float* __restrict__ x, const float* __restrict__ W0,
    const float* __restrict__ b0, const float* __restrict__ a_src0,
    const float* __restrict__ a_tgt0, float* __restrict__ proj0,
    float* __restrict__ ssrc0, float* __restrict__ stgt0) {
  __shared__ float smem[32 * 36 + 32 * 64];
  const int t = threadIdx.x;
  if (blockIdx.x < NNODES) {
    const int n = blockIdx.x;
    const int lane = t & 63, wid = t >> 6;
    int* wsum = (int*)smem;
    const float4* row = (const float4*)(mask + (size_t)n * NNODES);
    float4 v[4];
    int cnt = 0;
#pragma unroll
    for (int j = 0; j < 4; ++j) {
      v[j] = row[t + 256 * j];  // coalesced
      cnt += (v[j].x == 0.0f) + (v[j].y == 0.0f) + (v[j].z == 0.0f) +
             (v[j].w == 0.0f);
    }
    int xs = cnt;
#pragma unroll
    for (int o = 1; o < 64; o <<= 1) {
      int y = __shfl_up(xs, o);
      if (lane >= o) xs += y;
    }
    if (lane == 63) wsum[wid] = xs;
    __syncthreads();
    int base = 0;
    for (int w = 0; w < wid; ++w) base += wsum[w];
    int off = base + xs - cnt;
    if (t == 0) {
      int total = wsum[0] + wsum[1] + wsum[2] + wsum[3];
      deg[n] = total < CAP ? total : CAP;
    }
    int* dst = cols + (size_t)n * CAP;
#pragma unroll
    for (int j = 0; j < 4; ++j) {
      const int c0 = (t + 256 * j) * 4;
      float fv[4] = {v[j].x, v[j].y, v[j].z, v[j].w};
#pragma unroll
      for (int k = 0; k < 4; ++k) {
        if (fv[k] == 0.0f) {
          if (off < CAP) dst[off] = c0 + k;
          ++off;
        }
      }
    }
  } else {
    // gemm0: 32x64 tile, K=128, BK=32 chunks, 2x4 reg blocking + scores0
    float(*As)[36] = (float(*)[36])smem;
    float(*Ws)[64] = (float(*)[64])(smem + 32 * 36);
    const int bx = blockIdx.x - NNODES;
    const int brow = (bx & 127) * 32;
    const int head = bx >> 7;
    const int bcol = head * 64;
    const int tx = t & 15, ty = t >> 4;
    const int ar = t >> 3, ak = (t & 7) * 4;
    float acc[2][4] = {};
    for (int c = 0; c < 4; ++c) {
      const int k0 = c * 32;
      *(float4*)&As[ar][ak] =
          *(const float4*)&x[(size_t)(brow + ar) * 128 + k0 + ak];
#pragma unroll
      for (int q = 0; q < 2; ++q) {
        int i = t + q * 256;
        int k = i >> 4, c4 = (i & 15) * 4;
        *(float4*)&Ws[k][c4] =
            *(const float4*)&W0[(size_t)(k0 + k) * 512 + bcol + c4];
      }
      __syncthreads();
#pragma unroll 2
      for (int kk = 0; kk < 32; kk += 4) {
        float4 a0 = *(const float4*)&As[ty * 2 + 0][kk];
        float4 a1 = *(const float4*)&As[ty * 2 + 1][kk];
#pragma unroll
        for (int j = 0; j < 4; ++j) {
          float4 w = *(const float4*)&Ws[kk + j][tx * 4];
          float av0 = ((const float*)&a0)[j];
          float av1 = ((const float*)&a1)[j];
          acc[0][0] = fmaf(av0, w.x, acc[0][0]);
          acc[0][1] = fmaf(av0, w.y, acc[0][1]);
          acc[0][2] = fmaf(av0, w.z, acc[0][2]);
          acc[0][3] = fmaf(av0, w.w, acc[0][3]);
          acc[1][0] = fmaf(av1, w.x, acc[1][0]);
          acc[1][1] = fmaf(av1, w.y, acc[1][1]);
          acc[1][2] = fmaf(av1, w.z, acc[1][2]);
          acc[1][3] = fmaf(av1, w.w, acc[1][3]);
        }
      }
      __syncthreads();
    }
    const float4 bv = *(const float4*)&b0[bcol + tx * 4];
    const float4 as = *(const float4*)&a_src0[head * 64 + tx * 4];
    const float4 at = *(const float4*)&a_tgt0[head * 64 + tx * 4];
#pragma unroll
    for (int r = 0; r < 2; ++r) {
      float4 o;
      o.x = acc[r][0] + bv.x; o.y = acc[r][1] + bv.y;
      o.z = acc[r][2] + bv.z; o.w = acc[r][3] + bv.w;
      const size_t node = brow + ty * 2 + r;
      *(float4*)&proj0[node * 512 + bcol + tx * 4] = o;
      float ps = o.x * as.x + o.y * as.y + o.z * as.z + o.w * as.w;
      float pt = o.x * at.x + o.y * at.y + o.z * at.z + o.w * at.w;
#pragma unroll
      for (int m = 8; m; m >>= 1) {
        ps += __shfl_xor(ps, m);
        pt += __shfl_xor(pt, m);
      }
      if (tx == 0) {
        ssrc0[node * 8 + head] = ps;
        stgt0[node * 8 + head] = pt;
      }
    }
  }
}

// ---------------------------------------------------------------------------
// Fused D2, one block per node: attn layer 0 (H=8) -> h0row in LDS ->
// row-GEMM with W1 (row-local) -> +bias -> scores1.
// R12 lesson: break dep chains — 4-deep gather unroll w/ 4 accumulators;
// W1 loaded as float4 (4 k-rows per wave-load, 32 loads instead of 128).
// ---------------------------------------------------------------------------
__global__ __launch_bounds__(256) void attn8_gemm1_kernel(
    const float* __restrict__ proj0, const float* __restrict__ ssrc0,
    const float* __restrict__ stgt0, const int* __restrict__ deg,
    const int* __restrict__ cols, const float* __restrict__ W1,
    const float* __restrict__ b1, const float* __restrict__ a_src1,
    const float* __restrict__ a_tgt1, float* __restrict__ proj1,
    float* __restrict__ ssrc1, float* __restrict__ stgt1) {
  const int n = blockIdx.x;
  const int t = threadIdx.x;
  const int lane = t & 63, wid = t >> 6;
  __shared__ int sm_[CAP];        // 1 KB
  __shared__ float sw[CAP * 8];   // 8 KB
  __shared__ float sinv[8];
  __shared__ float h0row[512];    // 2 KB (grp1 partial buffer, then h0 row)
  __shared__ float pr[4][64];     // 1 KB gemm partials
  const int d = deg[n];
  for (int i = t; i < d; i += 256) sm_[i] = cols[(size_t)n * CAP + i];
  __syncthreads();
  for (int i = t; i < d * 8; i += 256) {
    int e = i >> 3, h = i & 7;
    float s = ssrc0[n * 8 + h] + stgt0[sm_[e] * 8 + h];
    sw[i] = s >= 0.f ? s : 0.2f * s;
  }
  __syncthreads();
  for (int h = wid; h < 8; h += 4) {  // each wave owns its heads (no race)
    float mx = -1e30f;
    for (int e = lane; e < d; e += 64) mx = fmaxf(mx, sw[e * 8 + h]);
#pragma unroll
    for (int o = 32; o; o >>= 1) mx = fmaxf(mx, __shfl_xor(mx, o));
    float sum = 0.f;
    for (int e = lane; e < d; e += 64) {
      float w = __expf(sw[e * 8 + h] - mx);
      sw[e * 8 + h] = w;
      sum += w;
    }
#pragma unroll
    for (int o = 32; o; o >>= 1) sum += __shfl_xor(sum, o);
    if (lane == 0) sinv[h] = 1.0f / sum;
  }
  __syncthreads();
  // gather h0row: 128 float4 slots, 2-way edge split, 4-deep ILP unroll
  const int f4 = t & 127, grp = t >> 7;
  const int hh = f4 >> 4;
  float4 a0 = make_float4(0.f, 0.f, 0.f, 0.f);
  float4 a1 = a0, a2 = a0, a3 = a0;
  int e = grp;
  for (; e + 6 < d; e += 8) {  // edges e, e+2, e+4, e+6 (stride-2 within grp)
    const int m0 = sm_[e], m1 = sm_[e + 2], m2 = sm_[e + 4], m3 = sm_[e + 6];
    const float w0 = sw[e * 8 + hh], w1 = sw[(e + 2) * 8 + hh];
    const float w2 = sw[(e + 4) * 8 + hh], w3 = sw[(e + 6) * 8 + hh];
    const float4 p0 = *(const float4*)&proj0[(size_t)m0 * 512 + f4 * 4];
    const float4 p1 = *(const float4*)&proj0[(size_t)m1 * 512 + f4 * 4];
    const float4 p2 = *(const float4*)&proj0[(size_t)m2 * 512 + f4 * 4];
    const float4 p3 = *(const float4*)&proj0[(size_t)m3 * 512 + f4 * 4];
    a0.x = fmaf(w0, p0.x, a0.x); a0.y = fmaf(w0, p0.y, a0.y);
    a0.z = fmaf(w0, p0.z, a0.z); a0.w = fmaf(w0, p0.w, a0.w);
    a1.x = fmaf(w1, p1.x, a1.x); a1.y = fmaf(w1, p1.y, a1.y);
    a1.z = fmaf(w1, p1.z, a1.z); a1.w = fmaf(w1, p1.w, a1.w);
    a2.x = fmaf(w2, p2.x, a2.x); a2.y = fmaf(w2, p2.y, a2.y);
    a2.z = fmaf(w2, p2.z, a2.z); a2.w = fmaf(w2, p2.w, a2.w);
    a3.x = fmaf(w3, p3.x, a3.x); a3.y = fmaf(w3, p3.y, a3.y);
    a3.z = fmaf(w3, p3.z, a3.z); a3.w = fmaf(w3, p3.w, a3.w);
  }
  for (; e < d; e += 2) {
    const float w = sw[e * 8 + hh];
    const float4 pv = *(const float4*)&proj0[(size_t)sm_[e] * 512 + f4 * 4];
    a0.x = fmaf(w, pv.x, a0.x); a0.y = fmaf(w, pv.y, a0.y);
    a0.z = fmaf(w, pv.z, a0.z); a0.w = fmaf(w, pv.w, a0.w);
  }
  float4 acc;
  acc.x = (a0.x + a1.x) + (a2.x + a3.x);
  acc.y = (a0.y + a1.y) + (a2.y + a3.y);
  acc.z = (a0.z + a1.z) + (a2.z + a3.z);
  acc.w = (a0.w + a1.w) + (a2.w + a3.w);
  float4* h0v = (float4*)h0row;
  if (grp == 1) h0v[f4] = acc;
  __syncthreads();
  if (grp == 0) {
    const float4 o2 = h0v[f4];
    const float s = sinv[hh];
    float4 o;
    o.x = (acc.x + o2.x) * s;
    o.y = (acc.y + o2.y) * s;
    o.z = (acc.z + o2.z) * s;
    o.w = (acc.w + o2.w) * s;
    h0v[f4] = o;
  }
  __syncthreads();
  // row-GEMM: wave w covers k in [w*128,(w+1)*128). float4 W1 loads:
  // lane l handles k = kbase + 4i + (l>>4), cols (l&15)*4..+3  (1KB/wave-load)
  {
    const int kbase = wid * 128;
    const int kofs = lane >> 4;       // 0..3
    const int c4 = (lane & 15) * 4;   // output col group
    float4 acc4 = make_float4(0.f, 0.f, 0.f, 0.f);
#pragma unroll 8
    for (int i = 0; i < 32; ++i) {
      const int k = kbase + i * 4 + kofs;
      const float4 w4 = *(const float4*)&W1[(size_t)k * 64 + c4];
      const float hv = h0row[k];
      acc4.x = fmaf(hv, w4.x, acc4.x);
      acc4.y = fmaf(hv, w4.y, acc4.y);
      acc4.z = fmaf(hv, w4.z, acc4.z);
      acc4.w = fmaf(hv, w4.w, acc4.w);
    }
    // sum the 4 k-offset groups (lanes l, l^16, l^32, l^48)
#pragma unroll
    for (int o = 16; o <= 32; o <<= 1) {
      acc4.x += __shfl_xor(acc4.x, o);
      acc4.y += __shfl_xor(acc4.y, o);
      acc4.z += __shfl_xor(acc4.z, o);
      acc4.w += __shfl_xor(acc4.w, o);
    }
    if (lane < 16) *(float4*)&pr[wid][c4] = acc4;
  }
  __syncthreads();
  if (wid == 0) {
    float v = pr[0][lane] + pr[1][lane] + pr[2][lane] + pr[3][lane] + b1[lane];
    proj1[(size_t)n * 64 + lane] = v;
    float ps = v * a_src1[lane];
    float pt = v * a_tgt1[lane];
#pragma unroll
    for (int o = 32; o; o >>= 1) {
      ps += __shfl_xor(ps, o);
      pt += __shfl_xor(pt, o);
    }
    if (lane == 0) {
      ssrc1[n] = ps;
      stgt1[n] = pt;
    }
  }
}

// ---------------------------------------------------------------------------
// Sparse attention, H=1: one wave per node; float4 gather, 4-way edge split.
// ---------------------------------------------------------------------------
__global__ void attn1_kernel(
    const float* __restrict__ proj, const float* __restrict__ s_src,
    const float* __restrict__ s_tgt, const int* __restrict__ deg,
    const int* __restrict__ cols, float* __restrict__ out) {
  const int n = blockIdx.x;
  const int tid = threadIdx.x;  // 64 threads = 1 wave
  __shared__ int sm_[CAP];
  __shared__ float sw[CAP];
  const int d = deg[n];
  for (int i = tid; i < d; i += 64) sm_[i] = cols[(size_t)n * CAP + i];
  __syncthreads();
  const float ssn = s_src[n];
  for (int i = tid; i < d; i += 64) {
    float s = ssn + s_tgt[sm_[i]];
    sw[i] = s >= 0.f ? s : 0.2f * s;
  }
  __syncthreads();
  float mx = -1e30f;
  for (int e = tid; e < d; e += 64) mx = fmaxf(mx, sw[e]);
#pragma unroll
  for (int o = 32; o; o >>= 1) mx = fmaxf(mx, __shfl_xor(mx, o));
  float sum = 0.f;
  for (int e = tid; e < d; e += 64) {
    float w = __expf(sw[e] - mx);
    sw[e] = w;
    sum += w;
  }
#pragma unroll
  for (int o = 32; o; o >>= 1) sum += __shfl_xor(sum, o);
  const float sinv = 1.0f / sum;
  __syncthreads();
  const int f4 = tid & 15, grp = tid >> 4;  // 16 float4 outputs, 4-way edges
  float4 a0 = make_float4(0.f, 0.f, 0.f, 0.f);
  float4 a1 = a0;
  int e = grp;
  for (; e + 4 < d; e += 8) {  // edges e, e+4 (stride-4 within grp), 2-deep ILP
    const float w0 = sw[e], w1 = sw[e + 4];
    const float4 p0 = *(const float4*)&proj[(size_t)sm_[e] * 64 + f4 * 4];
    const float4 p1 = *(const float4*)&proj[(size_t)sm_[e + 4] * 64 + f4 * 4];
    a0.x = fmaf(w0, p0.x, a0.x); a0.y = fmaf(w0, p0.y, a0.y);
    a0.z = fmaf(w0, p0.z, a0.z); a0.w = fmaf(w0, p0.w, a0.w);
    a1.x = fmaf(w1, p1.x, a1.x); a1.y = fmaf(w1, p1.y, a1.y);
    a1.z = fmaf(w1, p1.z, a1.z); a1.w = fmaf(w1, p1.w, a1.w);
  }
  for (; e < d; e += 4) {
    const float w = sw[e];
    const float4 pv = *(const float4*)&proj[(size_t)sm_[e] * 64 + f4 * 4];
    a0.x = fmaf(w, pv.x, a0.x); a0.y = fmaf(w, pv.y, a0.y);
    a0.z = fmaf(w, pv.z, a0.z); a0.w = fmaf(w, pv.w, a0.w);
  }
  float4 acc;
  acc.x = a0.x + a1.x; acc.y = a0.y + a1.y;
  acc.z = a0.z + a1.z; acc.w = a0.w + a1.w;
#pragma unroll
  for (int o = 16; o <= 32; o <<= 1) {
    acc.x += __shfl_xor(acc.x, o);
    acc.y += __shfl_xor(acc.y, o);
    acc.z += __shfl_xor(acc.z, o);
    acc.w += __shfl_xor(acc.w, o);
  }
  if (grp == 0) {
    acc.x *= sinv; acc.y *= sinv; acc.z *= sinv; acc.w *= sinv;
    *(float4*)&out[(size_t)n * 64 + f4 * 4] = acc;
  }
}

// ---------------------------------------------------------------------------
extern "C" void kernel_launch(void* const* d_in, const int* in_sizes, int n_in,
                              void* d_out, int out_size, void* d_ws, size_t ws_size,
                              hipStream_t stream) {
  const float* x      = (const float*)d_in[0];
  const float* mask   = (const float*)d_in[1];
  const float* W0     = (const float*)d_in[2];
  const float* b0     = (const float*)d_in[3];
  const float* a_src0 = (const float*)d_in[4];
  const float* a_tgt0 = (const float*)d_in[5];
  const float* W1     = (const float*)d_in[6];
  const float* b1     = (const float*)d_in[7];
  const float* a_src1 = (const float*)d_in[8];
  const float* a_tgt1 = (const float*)d_in[9];
  float* out = (float*)d_out;

  // workspace layout (~13.4 MB)
  float* ws    = (float*)d_ws;
  float* proj0 = ws;                          // 4096*512
  float* proj1 = proj0 + NNODES * 512;        // 4096*64
  float* ssrc0 = proj1 + NNODES * 64;         // 4096*8
  float* stgt0 = ssrc0 + NNODES * 8;          // 4096*8
  float* ssrc1 = stgt0 + NNODES * 8;          // 4096
  float* stgt1 = ssrc1 + NNODES;              // 4096
  int* deg  = (int*)(stgt1 + NNODES);         // 4096
  int* cols = deg + NNODES;                   // 4096*CAP

  // D1: edge extraction (4096 blocks) overlapped with gemm0+scores0 (1024)
  phase1_kernel<<<NNODES + 1024, 256, 0, stream>>>(
      mask, deg, cols, x, W0, b0, a_src0, a_tgt0, proj0, ssrc0, stgt0);
  // D2: attn0 + row-local gemm1 + bias + scores1, one block per node
  attn8_gemm1_kernel<<<NNODES, 256, 0, stream>>>(
      proj0, ssrc0, stgt0, deg, cols, W1, b1, a_src1, a_tgt1,
      proj1, ssrc1, stgt1);
  // D3: attn layer 1
  attn1_kernel<<<NNODES, 64, 0, stream>>>(proj1, ssrc1, stgt1, deg, cols, out);
}